// Round 3
// baseline (135.575 us; speedup 1.0000x reference)
//
#include <hip/hip_runtime.h>

// Problem:
//   pos:    [1, 64, 1024]   float32
//   events: [2, 64, 131072] float32
//   out:    [2, 64, 131072] float32
// Semantics: out[b,e,t] = events[b,e,t-d_e] for t>=d_e else 0,
// where d_e = argmax(pos[0,e,:]) * (131072/1024).
//
// Single fused kernel: every block recomputes its event's argmax locally
// (pos row = 4 KB, L2/LLC-resident), then does its slice of the shifted copy.
//
// R2 = R1 with the compile fix: __builtin_nontemporal_* requires a native
// vector type, not HIP_vector_type<float,4>. Use clang ext_vector float4
// (fx4) and reinterpret_cast. Experiment unchanged:
// MAXIMIZE MEMORY-LEVEL PARALLELISM — issue all 8 loads into registers
// first (32 VGPRs in flight/thread), then all 8 stores, nontemporal both
// ways (touch-once streams). If no-op vs 119 us, kernel is at its ~16 us
// traffic floor and dur_us is harness-dominated -> roofline.

#define N_EVENTS 64
#define START_SIZE 1024
#define N_SAMPLES 131072
#define BATCH 2
#define FACTOR (N_SAMPLES / START_SIZE)      // 128 samples per pos slot
#define ROW_LEN4 (N_SAMPLES / 4)             // 32768 float4 per row
#define BLOCKS_PER_ROW 16
#define THREADS 256
#define SWEEP (BLOCKS_PER_ROW * THREADS)     // 4096 float4 per full-grid sweep
#define ITERS (ROW_LEN4 / SWEEP)             // 8 float4 per thread

typedef float fx4 __attribute__((ext_vector_type(4)));

__global__ __launch_bounds__(256) void dirac_fused_kernel(
        const float4* __restrict__ pos4,     // [64, 256] float4
        const fx4* __restrict__ ev,          // [128, 32768] float4
        fx4* __restrict__ out) {
    const int row   = blockIdx.x >> 4;       // 0..127  (b*64+e)
    const int chunk = blockIdx.x & (BLOCKS_PER_ROW - 1);
    const int e     = row & (N_EVENTS - 1);
    const int lane  = threadIdx.x & 63;

    // ---- wave-local argmax over pos[e][0..1023] (first-occurrence ties) ----
    float v = -3.402823466e+38f;
    int   bi = 0x7fffffff;
    #pragma unroll
    for (int k = 0; k < 4; ++k) {
        const int f4 = k * 64 + lane;        // float4 index 0..255
        float4 p = pos4[e * 256 + f4];
        const int base = 4 * f4;
        if (p.x > v || (p.x == v && base     < bi)) { v = p.x; bi = base;     }
        if (p.y > v || (p.y == v && base + 1 < bi)) { v = p.y; bi = base + 1; }
        if (p.z > v || (p.z == v && base + 2 < bi)) { v = p.z; bi = base + 2; }
        if (p.w > v || (p.w == v && base + 3 < bi)) { v = p.w; bi = base + 3; }
    }
    #pragma unroll
    for (int off = 32; off >= 1; off >>= 1) {
        float ov = __shfl_xor(v, off, 64);
        int   oi = __shfl_xor(bi, off, 64);
        if (ov > v || (ov == v && oi < bi)) { v = ov; bi = oi; }
    }
    const int d4 = bi * (FACTOR / 4);        // float4-granular shift (mult of 32)

    // ---- shifted copy, all loads issued before any store (max MLP) ----
    const int rowbase = row * ROW_LEN4;
    const int colbase = chunk * THREADS + threadIdx.x;   // 0..4095

    fx4 vals[ITERS];
    #pragma unroll
    for (int it = 0; it < ITERS; ++it) {
        const int t4 = it * SWEEP + colbase;
        vals[it] = (fx4){0.f, 0.f, 0.f, 0.f};
        if (t4 >= d4) {
            vals[it] = __builtin_nontemporal_load(&ev[rowbase + (t4 - d4)]);
        }
    }
    #pragma unroll
    for (int it = 0; it < ITERS; ++it) {
        const int t4 = it * SWEEP + colbase;
        __builtin_nontemporal_store(vals[it], &out[rowbase + t4]);
    }
}

extern "C" void kernel_launch(void* const* d_in, const int* in_sizes, int n_in,
                              void* d_out, int out_size, void* d_ws, size_t ws_size,
                              hipStream_t stream) {
    const float4* pos4 = (const float4*)d_in[0];
    const fx4* ev = (const fx4*)d_in[1];
    fx4* out = (fx4*)d_out;

    const int nblocks = BATCH * N_EVENTS * BLOCKS_PER_ROW;   // 2048
    dirac_fused_kernel<<<nblocks, 256, 0, stream>>>(pos4, ev, out);
}

// Round 4
// 116.475 us; speedup vs baseline: 1.1640x; 1.1640x over previous
//
#include <hip/hip_runtime.h>

// Problem:
//   pos:    [1, 64, 1024]   float32
//   events: [2, 64, 131072] float32
//   out:    [2, 64, 131072] float32
// Semantics: out[b,e,t] = events[b,e,t-d_e] for t>=d_e else 0,
// where d_e = argmax(pos[0,e,:]) * (131072/1024).
//
// Single fused kernel: every block recomputes its event's argmax locally
// (pos row = 4 KB, L2/LLC-resident), then does its slice of the shifted copy.
//
// R3 post-mortem: nontemporal REGRESSED 119 -> 135.6 us. Counters showed
// the kernel at 42.5 us / 2 TB/s / 14% occupancy — running concurrently
// with the preceding 256 MiB poison-fill's LLC writeback drain (~40 us at
// ~4+ TB/s). The kernel is drain-starved, not internally limited; that is
// why R0 (load balance) and R1 (MLP) were null. nt stores bypassed LLC so
// our 64 MiB of out-writes no longer overwrote the dirty poison in-cache
// (+10 us extra HBM) and nt loads missed the freshly-restored events in
// LLC (+reads). R4 = revert to cache-allocating loads/stores; keep the
// batched-load structure (all 8 loads in flight before stores) and the
// stride-interleaved split. Expected: dur_us back to ~119, which is the
// harness-structural floor (2 poison fills ~83 us + restore ~20 us +
// kernel marginal ~15 us, all HBM-bound).

#define N_EVENTS 64
#define START_SIZE 1024
#define N_SAMPLES 131072
#define BATCH 2
#define FACTOR (N_SAMPLES / START_SIZE)      // 128 samples per pos slot
#define ROW_LEN4 (N_SAMPLES / 4)             // 32768 float4 per row
#define BLOCKS_PER_ROW 16
#define THREADS 256
#define SWEEP (BLOCKS_PER_ROW * THREADS)     // 4096 float4 per full-grid sweep
#define ITERS (ROW_LEN4 / SWEEP)             // 8 float4 per thread

__global__ __launch_bounds__(256) void dirac_fused_kernel(
        const float4* __restrict__ pos4,     // [64, 256] float4
        const float4* __restrict__ ev,       // [128, 32768] float4
        float4* __restrict__ out) {
    const int row   = blockIdx.x >> 4;       // 0..127  (b*64+e)
    const int chunk = blockIdx.x & (BLOCKS_PER_ROW - 1);
    const int e     = row & (N_EVENTS - 1);
    const int lane  = threadIdx.x & 63;

    // ---- wave-local argmax over pos[e][0..1023] (first-occurrence ties) ----
    float v = -3.402823466e+38f;
    int   bi = 0x7fffffff;
    #pragma unroll
    for (int k = 0; k < 4; ++k) {
        const int f4 = k * 64 + lane;        // float4 index 0..255
        float4 p = pos4[e * 256 + f4];
        const int base = 4 * f4;
        if (p.x > v || (p.x == v && base     < bi)) { v = p.x; bi = base;     }
        if (p.y > v || (p.y == v && base + 1 < bi)) { v = p.y; bi = base + 1; }
        if (p.z > v || (p.z == v && base + 2 < bi)) { v = p.z; bi = base + 2; }
        if (p.w > v || (p.w == v && base + 3 < bi)) { v = p.w; bi = base + 3; }
    }
    #pragma unroll
    for (int off = 32; off >= 1; off >>= 1) {
        float ov = __shfl_xor(v, off, 64);
        int   oi = __shfl_xor(bi, off, 64);
        if (ov > v || (ov == v && oi < bi)) { v = ov; bi = oi; }
    }
    const int d4 = bi * (FACTOR / 4);        // float4-granular shift (mult of 32)

    // ---- shifted copy, all loads issued before any store (max MLP),
    //      regular cache-allocating accesses (cooperate with LLC drain) ----
    const int rowbase = row * ROW_LEN4;
    const int colbase = chunk * THREADS + threadIdx.x;   // 0..4095

    float4 vals[ITERS];
    #pragma unroll
    for (int it = 0; it < ITERS; ++it) {
        const int t4 = it * SWEEP + colbase;
        vals[it] = make_float4(0.f, 0.f, 0.f, 0.f);
        if (t4 >= d4) {
            vals[it] = ev[rowbase + (t4 - d4)];
        }
    }
    #pragma unroll
    for (int it = 0; it < ITERS; ++it) {
        const int t4 = it * SWEEP + colbase;
        out[rowbase + t4] = vals[it];
    }
}

extern "C" void kernel_launch(void* const* d_in, const int* in_sizes, int n_in,
                              void* d_out, int out_size, void* d_ws, size_t ws_size,
                              hipStream_t stream) {
    const float4* pos4 = (const float4*)d_in[0];
    const float4* ev   = (const float4*)d_in[1];
    float4* out = (float4*)d_out;

    const int nblocks = BATCH * N_EVENTS * BLOCKS_PER_ROW;   // 2048
    dirac_fused_kernel<<<nblocks, 256, 0, stream>>>(pos4, ev, out);
}